// Round 8
// baseline (37.007 us; speedup 1.0000x reference)
//
#include <hip/hip_runtime.h>
#include <hip/hip_bf16.h>

#define NPE   512
#define F_IN  128
#define HDIM  16
#define ODIM  10

typedef __attribute__((ext_vector_type(8))) short short8;
typedef __attribute__((ext_vector_type(4))) float f32x4;

static __device__ __forceinline__ unsigned pkbf(float lo, float hi) {
  __hip_bfloat162 h = __float22bfloat162_rn(make_float2(lo, hi));
  unsigned r;
  __builtin_memcpy(&r, &h, 4);                     // v_cvt_pk_bf16_f32
  return r;
}
static __device__ __forceinline__ short f2bf(float f) {
  __hip_bfloat16 h = __float2bfloat16(f);
  short r;
  __builtin_memcpy(&r, &h, 2);
  return r;
}
static __device__ __forceinline__ float bflo(unsigned d) {
  return __builtin_bit_cast(float, d << 16);
}
static __device__ __forceinline__ float bfhi(unsigned d) {
  return __builtin_bit_cast(float, d & 0xffff0000u);
}
static __device__ __forceinline__ unsigned umin2(unsigned a, unsigned b) { return a < b ? a : b; }
static __device__ __forceinline__ unsigned umax2(unsigned a, unsigned b) { return a > b ? a : b; }

__global__ __launch_bounds__(512, 4) void gnet_fused(
    const int* __restrict__ coo, const float* __restrict__ x,
    const float* __restrict__ W1, const float* __restrict__ b1,
    const float* __restrict__ W2, const float* __restrict__ b2,
    float* __restrict__ out)
{
  __shared__ __align__(16) short    hbuf[NPE][24];    // 24 KB h1 bf16 / agg_r alias
  __shared__ __align__(16) short    stage_s[8][2048]; // 32 KB x-tile slabs; r_s alias after join
  __shared__ unsigned short cellof_s[NPE];
  __shared__ unsigned       cnt_s [256];
  __shared__ unsigned       scan_s[256];
  __shared__ unsigned       cur_s [256];
  __shared__ unsigned short bucket_s[NPE];
  __shared__ unsigned       top7_s[256][8];
  __shared__ unsigned       tile_c;
  __shared__ unsigned       sortflag;

  const int tid   = threadIdx.x;
  const int gbase = blockIdx.x * NPE;
  const int ln    = tid & 63;
  const int wv    = tid >> 6;
  const int lcol  = ln & 15;
  const int lkg   = ln >> 4;

  const int cx = coo[(gbase + tid) * 3 + 0];
  const int cy = coo[(gbase + tid) * 3 + 1];
  const int mycell = cy * 16 + cx;
  cellof_s[tid] = (unsigned short)mycell;
  if (tid == 0) { tile_c = 0; sortflag = 0; }
  __syncthreads();   // the ONLY barrier before the big join

  // W1 fragments (all waves; used in steal loop)
  short8 bw1[4];
#pragma unroll
  for (int s = 0; s < 4; ++s) {
#pragma unroll
    for (int e = 0; e < 8; ++e) {
      const int k = s * 32 + lkg * 8 + e;
      bw1[s][e] = f2bf(W1[k * HDIM + lcol]);
    }
  }

  // ---------------- wave 0: counting sort (lockstep, no block barriers)
  if (wv == 0) {
#pragma unroll
    for (int q = 0; q < 4; ++q) cnt_s[ln * 4 + q] = 0;
    __threadfence_block();
#pragma unroll
    for (int q = 0; q < 8; ++q)
      atomicAdd(&cnt_s[cellof_s[ln + q * 64]], 1u);
    __threadfence_block();
    const unsigned c0 = cnt_s[ln * 4 + 0], c1 = cnt_s[ln * 4 + 1];
    const unsigned c2 = cnt_s[ln * 4 + 2], c3 = cnt_s[ln * 4 + 3];
    const unsigned psum = c0 + c1 + c2 + c3;
    unsigned sv = psum;
#pragma unroll
    for (int off = 1; off < 64; off <<= 1) {
      unsigned u = __shfl_up(sv, off, 64);
      if (ln >= off) sv += u;
    }
    const unsigned basex = sv - psum;
    const unsigned e0 = basex + c0, e1 = e0 + c1, e2 = e1 + c2, e3 = e2 + c3;
    scan_s[ln * 4 + 0] = e0; cur_s[ln * 4 + 0] = e0 - c0;
    scan_s[ln * 4 + 1] = e1; cur_s[ln * 4 + 1] = e1 - c1;
    scan_s[ln * 4 + 2] = e2; cur_s[ln * 4 + 2] = e2 - c2;
    scan_s[ln * 4 + 3] = e3; cur_s[ln * 4 + 3] = e3 - c3;
    __threadfence_block();
#pragma unroll
    for (int q = 0; q < 8; ++q) {
      const int node = ln + q * 64;
      const unsigned slot = atomicAdd(&cur_s[cellof_s[node]], 1u);
      bucket_s[slot] = (unsigned short)node;
    }
    __threadfence_block();
    if (ln == 0) *(volatile unsigned*)&sortflag = 1u;
  } else if (wv < 4) {
    while (*(volatile unsigned*)&sortflag == 0u) __builtin_amdgcn_s_sleep(8);
    __threadfence_block();
  }

  // ---------------- waves 0-3: cell-level knn (one cell per thread)
  if (wv < 4 && cnt_s[tid] != 0) {
    const int ccx = tid & 15, ccy = tid >> 4;
    unsigned k0 = 0x7fffffffu, k1 = k0, k2 = k0, k3 = k0, k4 = k0, k5 = k0, k6 = k0;
    auto insert7 = [&](unsigned key) {
      if (key < k6) {
        k6 = key;
        unsigned lo, hi;
        lo = umin2(k5, k6); hi = umax2(k5, k6); k5 = lo; k6 = hi;
        lo = umin2(k4, k5); hi = umax2(k4, k5); k4 = lo; k5 = hi;
        lo = umin2(k3, k4); hi = umax2(k3, k4); k3 = lo; k4 = hi;
        lo = umin2(k2, k3); hi = umax2(k2, k3); k2 = lo; k3 = hi;
        lo = umin2(k1, k2); hi = umax2(k1, k2); k1 = lo; k2 = hi;
        lo = umin2(k0, k1); hi = umax2(k0, k1); k0 = lo; k1 = hi;
      }
    };
    auto scan_cell = [&](int c, unsigned kb) {
      const unsigned e = scan_s[c];
      const unsigned n = cnt_s[c];
      for (unsigned q = e - n; q < e; ++q) insert7(kb | (unsigned)bucket_s[q]);
    };
    scan_cell(tid, 0u);
    for (int r = 1; r <= 15; ++r) {
      const unsigned r2 = (unsigned)(r * r);
      if (r2 > (k6 >> 9)) break;
      for (int sg = 0; sg < 2; ++sg) {              // rows dy = ±r
        const int yy = ccy + (sg ? r : -r);
        if (yy < 0 || yy > 15) continue;
        const int xlo = ccx - r < 0 ? 0 : ccx - r;
        const int xhi = ccx + r > 15 ? 15 : ccx + r;
        for (int xx = xlo; xx <= xhi; ++xx) {
          const int dx = xx - ccx;
          const unsigned kb = (unsigned)(dx * dx + (int)r2) << 9;
          if (kb < k6) scan_cell(yy * 16 + xx, kb);
        }
      }
      for (int sg = 0; sg < 2; ++sg) {              // cols dx = ±r
        const int xx = ccx + (sg ? r : -r);
        if (xx < 0 || xx > 15) continue;
        const int ylo = ccy - r + 1 < 0 ? 0 : ccy - r + 1;
        const int yhi = ccy + r - 1 > 15 ? 15 : ccy + r - 1;
        for (int yy = ylo; yy <= yhi; ++yy) {
          const int dy = yy - ccy;
          const unsigned kb = (unsigned)(dy * dy + (int)r2) << 9;
          if (kb < k6) scan_cell(yy * 16 + xx, kb);
        }
      }
    }
    unsigned* tp = top7_s[tid];
    tp[0] = k0; tp[1] = k1; tp[2] = k2; tp[3] = k3; tp[4] = k4; tp[5] = k5; tp[6] = k6;
  }

  // ---------------- gemm1: register-prefetch steal loop, 32 tiles x 16 rows.
  // Contiguous 1 KB global loads; next tile's 8 loads stay in flight across
  // the current tile's cvt + ds_write + ds_read + MFMA (counted vmcnt).
  // Single wave-private 4 KB slab (DS ops of one wave are FIFO => WAR safe).
  {
    short* slab = &stage_s[wv][0];
    const int srow = ln >> 5;          // 0..1
    const int scol = (ln & 31) * 4;    // 0..124 (floats)

    auto steal = [&]() -> int {
      int t = 0;
      if (ln == 0) t = (int)atomicAdd(&tile_c, 1u);
      return __shfl(t, 0, 64);
    };
    auto issue = [&](float4* buf, int t) {
      const float4* q = reinterpret_cast<const float4*>(
          x + (size_t)(gbase + t * 16 + srow) * F_IN + scol);
#pragma unroll
      for (int j = 0; j < 8; ++j) buf[j] = q[(size_t)j * 64];  // +2 rows each
    };
    auto process = [&](const float4* buf, int t) {
      const int rb = t * 16;
#pragma unroll
      for (int j = 0; j < 8; ++j) {
        const unsigned lo = pkbf(buf[j].x, buf[j].y);
        const unsigned hi = pkbf(buf[j].z, buf[j].w);
        *reinterpret_cast<uint2*>(&slab[(2 * j + srow) * 128 + scol]) =
            make_uint2(lo, hi);
      }
      f32x4 acc = {0.f, 0.f, 0.f, 0.f};
#pragma unroll
      for (int s = 0; s < 4; ++s) {
        const short8 af = *reinterpret_cast<const short8*>(
            &slab[lcol * 128 + s * 32 + lkg * 8]);
        acc = __builtin_amdgcn_mfma_f32_16x16x32_bf16(af, bw1[s], acc, 0, 0, 0);
      }
#pragma unroll
      for (int i = 0; i < 4; ++i) {
        hbuf[rb + lkg * 4 + i][lcol] = f2bf(acc[i]);  // col=lane&15, row=(lane>>4)*4+i
      }
    };

    float4 bufA[8], bufB[8];
    int tA = steal();
    if (tA < 32) {
      issue(bufA, tA);
      for (;;) {
        const int tB = steal();
        if (tB < 32) issue(bufB, tB);     // in flight over process(A)
        process(bufA, tA);
        if (tB >= 32) break;
        const int tC = steal();
        if (tC < 32) issue(bufA, tC);     // in flight over process(B)
        process(bufB, tB);
        if (tC >= 32) break;
        tA = tC;
      }
    }
  }
  __syncthreads();   // join: hbuf(h1) + top7_s complete; stage slabs now dead

  short (*r_s)[16] = reinterpret_cast<short (*)[16]>(&stage_s[0][0]);  // 16 KB alias

  // ---------------- per-node neighbors from cell top-7 (branch-free self skip)
  const unsigned* tp = top7_s[mycell];
  const unsigned t0 = tp[0], t1 = tp[1], t2 = tp[2], t3 = tp[3];
  const unsigned t4 = tp[4], t5 = tp[5], t6 = tp[6];
  const unsigned selfkey = (unsigned)tid;
  int p = 7;
  p = (t6 == selfkey) ? 6 : p;
  p = (t5 == selfkey) ? 5 : p;
  p = (t4 == selfkey) ? 4 : p;
  p = (t3 == selfkey) ? 3 : p;
  p = (t2 == selfkey) ? 2 : p;
  p = (t1 == selfkey) ? 1 : p;
  p = (t0 == selfkey) ? 0 : p;
  const int nb0 = (int)((p > 0 ? t0 : t1) & 511u);
  const int nb1 = (int)((p > 1 ? t1 : t2) & 511u);
  const int nb2 = (int)((p > 2 ? t2 : t3) & 511u);
  const int nb3 = (int)((p > 3 ? t3 : t4) & 511u);
  const int nb4 = (int)((p > 4 ? t4 : t5) & 511u);
  const int nb5 = (int)((p > 5 ? t5 : t6) & 511u);
  const int rows[7] = {tid, nb0, nb1, nb2, nb3, nb4, nb5};

  // ---------------- Phase C: r = relu((self+6nbrs)/7 + b1) -> r_s (bf16)
  {
    float acc[HDIM];
#pragma unroll
    for (int o = 0; o < HDIM; ++o) acc[o] = 0.f;
#pragma unroll
    for (int r = 0; r < 7; ++r) {
      const uint4* hp = reinterpret_cast<const uint4*>(&hbuf[rows[r]][0]);
      const uint4 ha = hp[0];
      const uint4 hb = hp[1];
      const unsigned hd[8] = {ha.x, ha.y, ha.z, ha.w, hb.x, hb.y, hb.z, hb.w};
#pragma unroll
      for (int q = 0; q < 8; ++q) {
        acc[2 * q]     += bflo(hd[q]);
        acc[2 * q + 1] += bfhi(hd[q]);
      }
    }
    const float inv = 1.0f / 7.0f;
    unsigned pk[8];
#pragma unroll
    for (int q = 0; q < 8; ++q) {
      const float v0 = fmaxf(acc[2 * q]     * inv + b1[2 * q],     0.f);
      const float v1 = fmaxf(acc[2 * q + 1] * inv + b1[2 * q + 1], 0.f);
      pk[q] = pkbf(v0, v1);
    }
    uint4* rp = reinterpret_cast<uint4*>(&r_s[tid][0]);
    rp[0] = make_uint4(pk[0], pk[1], pk[2], pk[3]);
    rp[1] = make_uint4(pk[4], pk[5], pk[6], pk[7]);
  }
  __syncthreads();

  // ---------------- Phase C2: agg_r = (self+6nbrs r)/7 -> hbuf (h1 dead)
  // Linearity: A_norm (r @ W2) == (A_norm r) @ W2
  {
    float acc[HDIM];
#pragma unroll
    for (int o = 0; o < HDIM; ++o) acc[o] = 0.f;
#pragma unroll
    for (int r = 0; r < 7; ++r) {
      const uint4* hp = reinterpret_cast<const uint4*>(&r_s[rows[r]][0]);
      const uint4 ha = hp[0];
      const uint4 hb = hp[1];
      const unsigned hd[8] = {ha.x, ha.y, ha.z, ha.w, hb.x, hb.y, hb.z, hb.w};
#pragma unroll
      for (int q = 0; q < 8; ++q) {
        acc[2 * q]     += bflo(hd[q]);
        acc[2 * q + 1] += bfhi(hd[q]);
      }
    }
    const float inv = 1.0f / 7.0f;
    unsigned pk[8];
#pragma unroll
    for (int q = 0; q < 8; ++q) {
      pk[q] = pkbf(acc[2 * q] * inv, acc[2 * q + 1] * inv);
    }
    uint4* ap = reinterpret_cast<uint4*>(&hbuf[tid][0]);
    ap[0] = make_uint4(pk[0], pk[1], pk[2], pk[3]);
    ap[1] = make_uint4(pk[4], pk[5], pk[6], pk[7]);
  }
  __syncthreads();

  // ---------------- Phase D: out = agg_r @ W2 + b2 (MFMA, K=16 padded to 32)
  {
    short8 bw2 = {0, 0, 0, 0, 0, 0, 0, 0};
    if (lkg < 2 && lcol < ODIM) {
#pragma unroll
      for (int e = 0; e < 8; ++e) {
        const int k = lkg * 8 + e;
        bw2[e] = f2bf(W2[k * ODIM + lcol]);
      }
    }
    const float b2v = (lcol < ODIM) ? b2[lcol] : 0.f;
#pragma unroll
    for (int t = 0; t < 4; ++t) {
      const int nt = wv * 64 + t * 16;
      short8 af = {0, 0, 0, 0, 0, 0, 0, 0};
      if (lkg < 2) {
        af = *reinterpret_cast<const short8*>(&hbuf[nt + lcol][lkg * 8]);
      }
      f32x4 acc = {0.f, 0.f, 0.f, 0.f};
      acc = __builtin_amdgcn_mfma_f32_16x16x32_bf16(af, bw2, acc, 0, 0, 0);
      if (lcol < ODIM) {
#pragma unroll
        for (int i = 0; i < 4; ++i) {
          out[(size_t)(gbase + nt + lkg * 4 + i) * ODIM + lcol] = acc[i] + b2v;
        }
      }
    }
  }
}

extern "C" void kernel_launch(void* const* d_in, const int* in_sizes, int n_in,
                              void* d_out, int out_size, void* d_ws, size_t ws_size,
                              hipStream_t stream) {
  const int*   coo = (const int*)  d_in[0];
  const float* x   = (const float*)d_in[1];
  const float* W1  = (const float*)d_in[2];
  const float* b1  = (const float*)d_in[3];
  const float* W2  = (const float*)d_in[4];
  const float* b2  = (const float*)d_in[5];
  gnet_fused<<<dim3(512), dim3(512), 0, stream>>>(coo, x, W1, b1, W2, b2,
                                                  (float*)d_out);
}

// Round 9
// 32.140 us; speedup vs baseline: 1.1514x; 1.1514x over previous
//
#include <hip/hip_runtime.h>
#include <hip/hip_bf16.h>

#define NPE   512
#define F_IN  128
#define HDIM  16
#define ODIM  10

typedef __attribute__((ext_vector_type(8))) short short8;
typedef __attribute__((ext_vector_type(4))) float f32x4;

static __device__ __forceinline__ unsigned pkbf(float lo, float hi) {
  __hip_bfloat162 h = __float22bfloat162_rn(make_float2(lo, hi));
  unsigned r;
  __builtin_memcpy(&r, &h, 4);                     // v_cvt_pk_bf16_f32
  return r;
}
static __device__ __forceinline__ short f2bf(float f) {
  __hip_bfloat16 h = __float2bfloat16(f);
  short r;
  __builtin_memcpy(&r, &h, 2);
  return r;
}
static __device__ __forceinline__ float bflo(unsigned d) {
  return __builtin_bit_cast(float, d << 16);
}
static __device__ __forceinline__ float bfhi(unsigned d) {
  return __builtin_bit_cast(float, d & 0xffff0000u);
}
static __device__ __forceinline__ unsigned umin2(unsigned a, unsigned b) { return a < b ? a : b; }
static __device__ __forceinline__ unsigned umax2(unsigned a, unsigned b) { return a > b ? a : b; }

__global__ __launch_bounds__(512, 4) void gnet_fused(
    const int* __restrict__ coo, const float* __restrict__ x,
    const float* __restrict__ W1, const float* __restrict__ b1,
    const float* __restrict__ W2, const float* __restrict__ b2,
    float* __restrict__ out)
{
  __shared__ __align__(16) short    hbuf[NPE][24];    // 24 KB h1 bf16 / agg_r alias
  __shared__ __align__(16) short    stage_s[8][2048]; // 32 KB x-tile slabs; r_s alias after join
  __shared__ unsigned short cellof_s[NPE];
  __shared__ unsigned       cnt_s [256];
  __shared__ unsigned       scan_s[256];
  __shared__ unsigned       cur_s [256];
  __shared__ unsigned short bucket_s[NPE];
  __shared__ unsigned       top7_s[256][8];
  __shared__ unsigned       tile_c;
  __shared__ unsigned       sortflag;

  const int tid   = threadIdx.x;
  const int gbase = blockIdx.x * NPE;
  const int ln    = tid & 63;
  const int wv    = tid >> 6;
  const int lcol  = ln & 15;
  const int lkg   = ln >> 4;

  const int cx = coo[(gbase + tid) * 3 + 0];
  const int cy = coo[(gbase + tid) * 3 + 1];
  const int mycell = cy * 16 + cx;
  cellof_s[tid] = (unsigned short)mycell;
  if (tid == 0) { tile_c = 0; sortflag = 0; }
  __syncthreads();   // the ONLY barrier before the big join

  // W1 fragments (all waves; used in steal loop)
  short8 bw1[4];
#pragma unroll
  for (int s = 0; s < 4; ++s) {
#pragma unroll
    for (int e = 0; e < 8; ++e) {
      const int k = s * 32 + lkg * 8 + e;
      bw1[s][e] = f2bf(W1[k * HDIM + lcol]);
    }
  }

  // ---------------- wave 0: counting sort (lockstep, no block barriers)
  if (wv == 0) {
#pragma unroll
    for (int q = 0; q < 4; ++q) cnt_s[ln * 4 + q] = 0;
    __threadfence_block();
#pragma unroll
    for (int q = 0; q < 8; ++q)
      atomicAdd(&cnt_s[cellof_s[ln + q * 64]], 1u);
    __threadfence_block();
    const unsigned c0 = cnt_s[ln * 4 + 0], c1 = cnt_s[ln * 4 + 1];
    const unsigned c2 = cnt_s[ln * 4 + 2], c3 = cnt_s[ln * 4 + 3];
    const unsigned psum = c0 + c1 + c2 + c3;
    unsigned sv = psum;
#pragma unroll
    for (int off = 1; off < 64; off <<= 1) {
      unsigned u = __shfl_up(sv, off, 64);
      if (ln >= off) sv += u;
    }
    const unsigned basex = sv - psum;
    const unsigned e0 = basex + c0, e1 = e0 + c1, e2 = e1 + c2, e3 = e2 + c3;
    scan_s[ln * 4 + 0] = e0; cur_s[ln * 4 + 0] = e0 - c0;
    scan_s[ln * 4 + 1] = e1; cur_s[ln * 4 + 1] = e1 - c1;
    scan_s[ln * 4 + 2] = e2; cur_s[ln * 4 + 2] = e2 - c2;
    scan_s[ln * 4 + 3] = e3; cur_s[ln * 4 + 3] = e3 - c3;
    __threadfence_block();
#pragma unroll
    for (int q = 0; q < 8; ++q) {
      const int node = ln + q * 64;
      const unsigned slot = atomicAdd(&cur_s[cellof_s[node]], 1u);
      bucket_s[slot] = (unsigned short)node;
    }
    __threadfence_block();
    if (ln == 0) *(volatile unsigned*)&sortflag = 1u;
  } else if (wv < 4) {
    while (*(volatile unsigned*)&sortflag == 0u) __builtin_amdgcn_s_sleep(8);
    __threadfence_block();
  }

  // ---------------- waves 0-3: cell-level knn (one cell per thread)
  if (wv < 4 && cnt_s[tid] != 0) {
    const int ccx = tid & 15, ccy = tid >> 4;
    unsigned k0 = 0x7fffffffu, k1 = k0, k2 = k0, k3 = k0, k4 = k0, k5 = k0, k6 = k0;
    auto insert7 = [&](unsigned key) {
      if (key < k6) {
        k6 = key;
        unsigned lo, hi;
        lo = umin2(k5, k6); hi = umax2(k5, k6); k5 = lo; k6 = hi;
        lo = umin2(k4, k5); hi = umax2(k4, k5); k4 = lo; k5 = hi;
        lo = umin2(k3, k4); hi = umax2(k3, k4); k3 = lo; k4 = hi;
        lo = umin2(k2, k3); hi = umax2(k2, k3); k2 = lo; k3 = hi;
        lo = umin2(k1, k2); hi = umax2(k1, k2); k1 = lo; k2 = hi;
        lo = umin2(k0, k1); hi = umax2(k0, k1); k0 = lo; k1 = hi;
      }
    };
    auto scan_cell = [&](int c, unsigned kb) {
      const unsigned e = scan_s[c];
      const unsigned n = cnt_s[c];
      for (unsigned q = e - n; q < e; ++q) insert7(kb | (unsigned)bucket_s[q]);
    };
    scan_cell(tid, 0u);
    for (int r = 1; r <= 15; ++r) {
      const unsigned r2 = (unsigned)(r * r);
      if (r2 > (k6 >> 9)) break;
      for (int sg = 0; sg < 2; ++sg) {              // rows dy = ±r
        const int yy = ccy + (sg ? r : -r);
        if (yy < 0 || yy > 15) continue;
        const int xlo = ccx - r < 0 ? 0 : ccx - r;
        const int xhi = ccx + r > 15 ? 15 : ccx + r;
        for (int xx = xlo; xx <= xhi; ++xx) {
          const int dx = xx - ccx;
          const unsigned kb = (unsigned)(dx * dx + (int)r2) << 9;
          if (kb < k6) scan_cell(yy * 16 + xx, kb);
        }
      }
      for (int sg = 0; sg < 2; ++sg) {              // cols dx = ±r
        const int xx = ccx + (sg ? r : -r);
        if (xx < 0 || xx > 15) continue;
        const int ylo = ccy - r + 1 < 0 ? 0 : ccy - r + 1;
        const int yhi = ccy + r - 1 > 15 ? 15 : ccy + r - 1;
        for (int yy = ylo; yy <= yhi; ++yy) {
          const int dy = yy - ccy;
          const unsigned kb = (unsigned)(dy * dy + (int)r2) << 9;
          if (kb < k6) scan_cell(yy * 16 + xx, kb);
        }
      }
    }
    unsigned* tp = top7_s[tid];
    tp[0] = k0; tp[1] = k1; tp[2] = k2; tp[3] = k3; tp[4] = k4; tp[5] = k5; tp[6] = k6;
  }

  // ---------------- gemm1 steal loop with LDS staging: 32 tiles x 16 rows.
  // Simple in-order body (r7 structure — BW-bound, depth adds nothing).
  // setprio(1) around the compute segment: steal-based waves are phase-
  // diverse, so prioritizing the processing wave tightens the stream.
  {
    short* slab = &stage_s[wv][0];
    for (;;) {
      int t = 0;
      if (ln == 0) t = (int)atomicAdd(&tile_c, 1u);
      t = __shfl(t, 0, 64);
      if (t >= 32) break;
      const int rb = t * 16;
      const int srow = ln >> 5;          // 0..1
      const int scol = (ln & 31) * 4;    // 0..124
      float4 v[8];
#pragma unroll
      for (int j = 0; j < 8; ++j) {
        v[j] = *reinterpret_cast<const float4*>(
            x + (size_t)(gbase + rb + 2 * j + srow) * F_IN + scol);
      }
      __builtin_amdgcn_s_setprio(1);
#pragma unroll
      for (int j = 0; j < 8; ++j) {
        const unsigned lo = pkbf(v[j].x, v[j].y);
        const unsigned hi = pkbf(v[j].z, v[j].w);
        *reinterpret_cast<uint2*>(&slab[(2 * j + srow) * 128 + scol]) =
            make_uint2(lo, hi);
      }
      f32x4 acc = {0.f, 0.f, 0.f, 0.f};
#pragma unroll
      for (int s = 0; s < 4; ++s) {
        const short8 af = *reinterpret_cast<const short8*>(
            &slab[lcol * 128 + s * 32 + lkg * 8]);
        acc = __builtin_amdgcn_mfma_f32_16x16x32_bf16(af, bw1[s], acc, 0, 0, 0);
      }
#pragma unroll
      for (int i = 0; i < 4; ++i) {
        hbuf[rb + lkg * 4 + i][lcol] = f2bf(acc[i]);  // col=lane&15, row=(lane>>4)*4+i
      }
      __builtin_amdgcn_s_setprio(0);
    }
  }
  __syncthreads();   // join: hbuf(h1) + top7_s complete; stage slabs now dead

  short (*r_s)[16] = reinterpret_cast<short (*)[16]>(&stage_s[0][0]);  // 16 KB alias

  // ---------------- per-node neighbors from cell top-7 (branch-free self skip)
  const unsigned* tp = top7_s[mycell];
  const unsigned t0 = tp[0], t1 = tp[1], t2 = tp[2], t3 = tp[3];
  const unsigned t4 = tp[4], t5 = tp[5], t6 = tp[6];
  const unsigned selfkey = (unsigned)tid;
  int p = 7;
  p = (t6 == selfkey) ? 6 : p;
  p = (t5 == selfkey) ? 5 : p;
  p = (t4 == selfkey) ? 4 : p;
  p = (t3 == selfkey) ? 3 : p;
  p = (t2 == selfkey) ? 2 : p;
  p = (t1 == selfkey) ? 1 : p;
  p = (t0 == selfkey) ? 0 : p;
  const int nb0 = (int)((p > 0 ? t0 : t1) & 511u);
  const int nb1 = (int)((p > 1 ? t1 : t2) & 511u);
  const int nb2 = (int)((p > 2 ? t2 : t3) & 511u);
  const int nb3 = (int)((p > 3 ? t3 : t4) & 511u);
  const int nb4 = (int)((p > 4 ? t4 : t5) & 511u);
  const int nb5 = (int)((p > 5 ? t5 : t6) & 511u);
  const int rows[7] = {tid, nb0, nb1, nb2, nb3, nb4, nb5};

  // ---------------- Phase C: r = relu((self+6nbrs)/7 + b1) -> r_s (bf16)
  {
    float acc[HDIM];
#pragma unroll
    for (int o = 0; o < HDIM; ++o) acc[o] = 0.f;
#pragma unroll
    for (int r = 0; r < 7; ++r) {
      const uint4* hp = reinterpret_cast<const uint4*>(&hbuf[rows[r]][0]);
      const uint4 ha = hp[0];
      const uint4 hb = hp[1];
      const unsigned hd[8] = {ha.x, ha.y, ha.z, ha.w, hb.x, hb.y, hb.z, hb.w};
#pragma unroll
      for (int q = 0; q < 8; ++q) {
        acc[2 * q]     += bflo(hd[q]);
        acc[2 * q + 1] += bfhi(hd[q]);
      }
    }
    const float inv = 1.0f / 7.0f;
    unsigned pk[8];
#pragma unroll
    for (int q = 0; q < 8; ++q) {
      const float v0 = fmaxf(acc[2 * q]     * inv + b1[2 * q],     0.f);
      const float v1 = fmaxf(acc[2 * q + 1] * inv + b1[2 * q + 1], 0.f);
      pk[q] = pkbf(v0, v1);
    }
    uint4* rp = reinterpret_cast<uint4*>(&r_s[tid][0]);
    rp[0] = make_uint4(pk[0], pk[1], pk[2], pk[3]);
    rp[1] = make_uint4(pk[4], pk[5], pk[6], pk[7]);
  }
  __syncthreads();

  // ---------------- Phase C2: agg_r = (self+6nbrs r)/7 -> hbuf (h1 dead)
  // Linearity: A_norm (r @ W2) == (A_norm r) @ W2
  {
    float acc[HDIM];
#pragma unroll
    for (int o = 0; o < HDIM; ++o) acc[o] = 0.f;
#pragma unroll
    for (int r = 0; r < 7; ++r) {
      const uint4* hp = reinterpret_cast<const uint4*>(&r_s[rows[r]][0]);
      const uint4 ha = hp[0];
      const uint4 hb = hp[1];
      const unsigned hd[8] = {ha.x, ha.y, ha.z, ha.w, hb.x, hb.y, hb.z, hb.w};
#pragma unroll
      for (int q = 0; q < 8; ++q) {
        acc[2 * q]     += bflo(hd[q]);
        acc[2 * q + 1] += bfhi(hd[q]);
      }
    }
    const float inv = 1.0f / 7.0f;
    unsigned pk[8];
#pragma unroll
    for (int q = 0; q < 8; ++q) {
      pk[q] = pkbf(acc[2 * q] * inv, acc[2 * q + 1] * inv);
    }
    uint4* ap = reinterpret_cast<uint4*>(&hbuf[tid][0]);
    ap[0] = make_uint4(pk[0], pk[1], pk[2], pk[3]);
    ap[1] = make_uint4(pk[4], pk[5], pk[6], pk[7]);
  }
  __syncthreads();

  // ---------------- Phase D: out = agg_r @ W2 + b2 (MFMA, K=16 padded to 32)
  {
    short8 bw2 = {0, 0, 0, 0, 0, 0, 0, 0};
    if (lkg < 2 && lcol < ODIM) {
#pragma unroll
      for (int e = 0; e < 8; ++e) {
        const int k = lkg * 8 + e;
        bw2[e] = f2bf(W2[k * ODIM + lcol]);
      }
    }
    const float b2v = (lcol < ODIM) ? b2[lcol] : 0.f;
#pragma unroll
    for (int t = 0; t < 4; ++t) {
      const int nt = wv * 64 + t * 16;
      short8 af = {0, 0, 0, 0, 0, 0, 0, 0};
      if (lkg < 2) {
        af = *reinterpret_cast<const short8*>(&hbuf[nt + lcol][lkg * 8]);
      }
      f32x4 acc = {0.f, 0.f, 0.f, 0.f};
      acc = __builtin_amdgcn_mfma_f32_16x16x32_bf16(af, bw2, acc, 0, 0, 0);
      if (lcol < ODIM) {
#pragma unroll
        for (int i = 0; i < 4; ++i) {
          // NT store: out is never re-read — keep L3 capacity for x retention
          __builtin_nontemporal_store(
              acc[i] + b2v,
              out + (size_t)(gbase + nt + lkg * 4 + i) * ODIM + lcol);
        }
      }
    }
  }
}

extern "C" void kernel_launch(void* const* d_in, const int* in_sizes, int n_in,
                              void* d_out, int out_size, void* d_ws, size_t ws_size,
                              hipStream_t stream) {
  const int*   coo = (const int*)  d_in[0];
  const float* x   = (const float*)d_in[1];
  const float* W1  = (const float*)d_in[2];
  const float* b1  = (const float*)d_in[3];
  const float* W2  = (const float*)d_in[4];
  const float* b2  = (const float*)d_in[5];
  gnet_fused<<<dim3(512), dim3(512), 0, stream>>>(coo, x, W1, b1, W2, b2,
                                                  (float*)d_out);
}